// Round 12
// baseline (3094.788 us; speedup 1.0000x reference)
//
#include <hip/hip_runtime.h>
#include <math.h>

#define BB 64
#define TT 1024
#define DD 32
#define GG 128   // 4*D
#define VOCABN 10000
#define QLEN 100
#define REP 16   // measurement round: idempotent x16 repeat in suspect kernels

typedef short short8 __attribute__((ext_vector_type(8)));   // 8 bf16 in 4 VGPRs
typedef float floatx4 __attribute__((ext_vector_type(4)));
typedef unsigned short u16;

__device__ __forceinline__ float fsig(float x) {
    return __builtin_amdgcn_rcpf(1.0f + __expf(-x));
}
__device__ __forceinline__ float readlane_f(float v, int l) {
    return __int_as_float(__builtin_amdgcn_readlane(__float_as_int(v), l));
}
__device__ __forceinline__ u16 f2bf_rne(float x) {
    unsigned u = __float_as_uint(x);
    u += 0x7FFF + ((u >> 16) & 1);
    return (u16)(u >> 16);
}
__device__ __forceinline__ float bf2f(u16 s) {
    return __uint_as_float(((unsigned)s) << 16);
}

// ---------------------------------------------------------------------------
// Kernel 1: xg — body repeated x16 (idempotent) for measurement.
// ---------------------------------------------------------------------------
__global__ __launch_bounds__(128) void k_xg(const int* __restrict__ ids,
                                            const float* __restrict__ emb,
                                            const float* __restrict__ klstm,
                                            const float* __restrict__ bias,
                                            float* __restrict__ xg) {
    const int j = threadIdx.x;  // 0..127
    float kc[DD];
#pragma unroll
    for (int d = 0; d < DD; ++d) kc[d] = klstm[d * GG + j];
    const float bj = bias[j];
    __shared__ float e4[4][DD];
    const int PPB = (BB * TT) / gridDim.x;  // 128 tokens per block
    const int p0 = blockIdx.x * PPB;
#pragma unroll 1
    for (int rep = 0; rep < REP; ++rep) {
        for (int p = p0; p < p0 + PPB; p += 4) {
            {
                int tok = p + (j >> 5);
                int id = ids[tok];
                if ((unsigned)id >= VOCABN) id = 0;
                e4[j >> 5][j & 31] = emb[id * DD + (j & 31)];
            }
            __syncthreads();
#pragma unroll
            for (int i = 0; i < 4; ++i) {
                float z = bj;
#pragma unroll
                for (int d = 0; d < DD; ++d) z += e4[i][d] * kc[d];
                xg[(size_t)(p + i) * GG + j] = z;
            }
            __syncthreads();
        }
    }
}

// ---------------------------------------------------------------------------
// Kernel 2: LSTM scan — R3-EXACT (311 µs proven) + fused queue. NO repeats
// (its cost is known). R10's all-4-gate variant reverted (443 µs, falsified
// the shfl-dominance theory: marginal FMA cost ~4.8cyc, shfls not dominant).
// ---------------------------------------------------------------------------
#define UU 8
__global__
__attribute__((amdgpu_flat_work_group_size(64, 64)))
__attribute__((amdgpu_waves_per_eu(1, 1)))
void k_lstm_scan(const float* __restrict__ xg,
                 const float* __restrict__ rk,
                 float* __restrict__ hout,
                 const int* __restrict__ ids,
                 int* __restrict__ list,
                 float* __restrict__ outq) {
    const int b = blockIdx.x;
    const int l = threadIdx.x;       // 0..63
    if (b >= BB) {
        const int4* v4 = (const int4*)ids;
        const int C4 = (BB * TT) / 4 / 64;
        const int b4 = l * C4;
        int cnt = 0;
#pragma unroll 4
        for (int i = 0; i < C4; ++i) {
            int4 v = v4[b4 + i];
            cnt += (v.x == 0 || (unsigned)v.x >= VOCABN);
            cnt += (v.y == 0 || (unsigned)v.y >= VOCABN);
            cnt += (v.z == 0 || (unsigned)v.z >= VOCABN);
            cnt += (v.w == 0 || (unsigned)v.w >= VOCABN);
        }
        int scan = cnt;
#pragma unroll
        for (int o = 1; o < 64; o <<= 1) {
            int nn = __shfl_up(scan, o);
            if (l >= o) scan += nn;
        }
        const int total = __shfl(scan, 63);
        int off = scan - cnt;
        const int base = l * (C4 * 4);
#pragma unroll 4
        for (int i = 0; i < C4; ++i) {
            int4 v = v4[b4 + i];
            if (v.x == 0 || (unsigned)v.x >= VOCABN) list[off++] = base + 4 * i;
            if (v.y == 0 || (unsigned)v.y >= VOCABN) list[off++] = base + 4 * i + 1;
            if (v.z == 0 || (unsigned)v.z >= VOCABN) list[off++] = base + 4 * i + 2;
            if (v.w == 0 || (unsigned)v.w >= VOCABN) list[off++] = base + 4 * i + 3;
        }
        __threadfence();
        const int Kc = total < QLEN ? total : QLEN;
        for (int t = l; t < QLEN; t += 64) {
            float ii = -1.0f, jj = -1.0f;
            if (t >= QLEN - Kc) {
                int pos = list[total - QLEN + t];
                ii = (float)(pos >> 10);
                jj = (float)(pos & (TT - 1));
            }
            outq[2 * t] = ii;
            outq[2 * t + 1] = jj;
        }
        return;
    }
    const int d = l & 31;
    const bool hi = l >= 32;
    const int ga = (hi ? 32 : 0) + d;
    const int gb = (hi ? 96 : 64) + d;
    float rka[DD], rkb[DD];
#pragma unroll
    for (int k = 0; k < DD; ++k) { rka[k] = rk[k * GG + ga]; rkb[k] = rk[k * GG + gb]; }
    const float* xgb = xg + (size_t)b * TT * GG;
    float* hb = hout + (size_t)b * TT * DD;

    float pa[UU], pb[UU];
#pragma unroll
    for (int u = 0; u < UU; ++u) { pa[u] = xgb[u * GG + ga]; pb[u] = xgb[u * GG + gb]; }

    float h = 0.0f, c = 0.0f;
    for (int t0 = 0; t0 < TT; t0 += UU) {
        float na[UU], nb[UU];
        const int tn0 = (t0 + UU < TT) ? (t0 + UU) : t0;
#pragma unroll
        for (int u = 0; u < UU; ++u) {
            na[u] = xgb[(tn0 + u) * GG + ga];
            nb[u] = xgb[(tn0 + u) * GG + gb];
        }
#pragma unroll
        for (int u = 0; u < UU; ++u) {
            float za0 = pa[u], zb0 = pb[u];
            float za1 = 0.f, za2 = 0.f, za3 = 0.f;
            float zb1 = 0.f, zb2 = 0.f, zb3 = 0.f;
#pragma unroll
            for (int k = 0; k < DD; k += 4) {
                float h0 = readlane_f(h, k);
                float h1 = readlane_f(h, k + 1);
                float h2 = readlane_f(h, k + 2);
                float h3 = readlane_f(h, k + 3);
                za0 = fmaf(h0, rka[k], za0);     zb0 = fmaf(h0, rkb[k], zb0);
                za1 = fmaf(h1, rka[k + 1], za1); zb1 = fmaf(h1, rkb[k + 1], zb1);
                za2 = fmaf(h2, rka[k + 2], za2); zb2 = fmaf(h2, rkb[k + 2], zb2);
                za3 = fmaf(h3, rka[k + 3], za3); zb3 = fmaf(h3, rkb[k + 3], zb3);
            }
            float za = (za0 + za1) + (za2 + za3);
            float zb = (zb0 + zb1) + (zb2 + zb3);
            float a = fsig(za);
            float zbm = hi ? zb : 2.0f * zb;
            float s2 = fsig(zbm);
            float bv = hi ? s2 : 2.0f * s2 - 1.0f;
            float fg = __shfl_xor(a, 32);
            float og = __shfl_xor(bv, 32);
            c = fmaf(fg, c, a * bv);
            float tc = 2.0f * fsig(2.0f * c) - 1.0f;
            h = og * tc;
            if (!hi) hb[(t0 + u) * DD + d] = h;
        }
#pragma unroll
        for (int u = 0; u < UU; ++u) { pa[u] = na[u]; pb[u] = nb[u]; }
    }
}

// ---------------------------------------------------------------------------
// Kernel 2.5: cvt — body repeated x16 (idempotent) for measurement.
// ---------------------------------------------------------------------------
__global__ __launch_bounds__(256) void k_cvt(const float* __restrict__ h,
                                             u16* __restrict__ hh, u16* __restrict__ hl,
                                             u16* __restrict__ th, u16* __restrict__ tl) {
    const int b = blockIdx.x >> 2;
    const int seg = blockIdx.x & 3;
    const int tid = threadIdx.x;
    const float* hsrc = h + (size_t)b * TT * DD;
    const size_t rb = (size_t)b * TT * DD;
    const size_t tb = (size_t)b * DD * TT;
    __shared__ float tile[64][33];
#pragma unroll 1
    for (int rep = 0; rep < REP; ++rep) {
        for (int t0 = seg * 256; t0 < seg * 256 + 256; t0 += 64) {
#pragma unroll
            for (int n = 0; n < 2; ++n) {
                int idx = tid + n * 256;
                int row = idx >> 3, c4 = idx & 7;
                float4 v = *(const float4*)&hsrc[(size_t)(t0 + row) * DD + c4 * 4];
                float xs[4] = {v.x, v.y, v.z, v.w};
                u16 hi4[4], lo4[4];
#pragma unroll
                for (int i = 0; i < 4; ++i) {
                    tile[row][c4 * 4 + i] = xs[i];
                    hi4[i] = f2bf_rne(xs[i]);
                    lo4[i] = f2bf_rne(xs[i] - bf2f(hi4[i]));
                }
                ushort4 hv = {hi4[0], hi4[1], hi4[2], hi4[3]};
                ushort4 lv = {lo4[0], lo4[1], lo4[2], lo4[3]};
                *(ushort4*)&hh[rb + (size_t)(t0 + row) * DD + c4 * 4] = hv;
                *(ushort4*)&hl[rb + (size_t)(t0 + row) * DD + c4 * 4] = lv;
            }
            __syncthreads();
#pragma unroll
            for (int n = 0; n < 8; ++n) {
                int flat = tid + n * 256;
                int d = flat >> 6, tt = flat & 63;
                float x = tile[tt][d];
                u16 hv = f2bf_rne(x);
                u16 lv = f2bf_rne(x - bf2f(hv));
                th[tb + (size_t)d * TT + t0 + tt] = hv;
                tl[tb + (size_t)d * TT + t0 + tt] = lv;
            }
            __syncthreads();
        }
    }
}

// ---------------------------------------------------------------------------
// Kernel 3: attention on MFMA — body repeated x16 for measurement.
// ---------------------------------------------------------------------------
__global__ __launch_bounds__(256) void k_attn(const u16* __restrict__ hh,
                                              const u16* __restrict__ hl,
                                              const u16* __restrict__ th,
                                              const u16* __restrict__ tl,
                                              float* __restrict__ ctx) {
    __shared__ u16 plds[4 * 16 * 40];
    const int tid = threadIdx.x;
    const int w = tid >> 6;
    const int l = tid & 63;
    const int m = l & 15;
    const int g = l >> 4;
    const int b = blockIdx.x >> 4;
    const int qt = (blockIdx.x & 15) * 4 + w;
    const int q0 = qt * 16;
    const size_t rb = (size_t)b * TT * DD;
    const size_t tb = (size_t)b * DD * TT;

    const short8 Qh = *(const short8*)&hh[rb + (size_t)(q0 + m) * DD + g * 8];
    const short8 Ql = *(const short8*)&hl[rb + (size_t)(q0 + m) * DD + g * 8];
    short8 ONES;
#pragma unroll
    for (int j = 0; j < 8; ++j) ONES[j] = (short)0x3F80;
    u16* mylds = plds + w * (16 * 40);

#pragma unroll 1
    for (int rep = 0; rep < REP; ++rep) {
        floatx4 c0 = {0.f, 0.f, 0.f, 0.f};
        floatx4 c1 = {0.f, 0.f, 0.f, 0.f};
        floatx4 la = {0.f, 0.f, 0.f, 0.f};
#pragma unroll 2
        for (int kp = 0; kp < 32; ++kp) {
            const int k0 = kp * 32;
            const short8 KhA = *(const short8*)&hh[rb + (size_t)(k0 + m) * DD + g * 8];
            const short8 KlA = *(const short8*)&hl[rb + (size_t)(k0 + m) * DD + g * 8];
            const short8 KhB = *(const short8*)&hh[rb + (size_t)(k0 + 16 + m) * DD + g * 8];
            const short8 KlB = *(const short8*)&hl[rb + (size_t)(k0 + 16 + m) * DD + g * 8];
            floatx4 sA = {0.f, 0.f, 0.f, 0.f};
            floatx4 sB = {0.f, 0.f, 0.f, 0.f};
            sA = __builtin_amdgcn_mfma_f32_16x16x32_bf16(Qh, KhA, sA, 0, 0, 0);
            sA = __builtin_amdgcn_mfma_f32_16x16x32_bf16(Qh, KlA, sA, 0, 0, 0);
            sA = __builtin_amdgcn_mfma_f32_16x16x32_bf16(Ql, KhA, sA, 0, 0, 0);
            sB = __builtin_amdgcn_mfma_f32_16x16x32_bf16(Qh, KhB, sB, 0, 0, 0);
            sB = __builtin_amdgcn_mfma_f32_16x16x32_bf16(Qh, KlB, sB, 0, 0, 0);
            sB = __builtin_amdgcn_mfma_f32_16x16x32_bf16(Ql, KhB, sB, 0, 0, 0);
#pragma unroll
            for (int r = 0; r < 4; ++r) {
                mylds[(g * 4 + r) * 40 + m]      = f2bf_rne(__expf(sA[r]));
                mylds[(g * 4 + r) * 40 + 16 + m] = f2bf_rne(__expf(sB[r]));
            }
            const short8 P = *(const short8*)&mylds[m * 40 + g * 8];
            const short8 Vh0 = *(const short8*)&th[tb + (size_t)m * TT + k0 + g * 8];
            const short8 Vl0 = *(const short8*)&tl[tb + (size_t)m * TT + k0 + g * 8];
            const short8 Vh1 = *(const short8*)&th[tb + (size_t)(16 + m) * TT + k0 + g * 8];
            const short8 Vl1 = *(const short8*)&tl[tb + (size_t)(16 + m) * TT + k0 + g * 8];
            c0 = __builtin_amdgcn_mfma_f32_16x16x32_bf16(P, Vh0, c0, 0, 0, 0);
            c0 = __builtin_amdgcn_mfma_f32_16x16x32_bf16(P, Vl0, c0, 0, 0, 0);
            c1 = __builtin_amdgcn_mfma_f32_16x16x32_bf16(P, Vh1, c1, 0, 0, 0);
            c1 = __builtin_amdgcn_mfma_f32_16x16x32_bf16(P, Vl1, c1, 0, 0, 0);
            la = __builtin_amdgcn_mfma_f32_16x16x32_bf16(P, ONES, la, 0, 0, 0);
        }
#pragma unroll
        for (int r = 0; r < 4; ++r) {
            float linv = __builtin_amdgcn_rcpf(la[r]);
            float* crow = ctx + rb + (size_t)(q0 + g * 4 + r) * DD;
            crow[m]      = c0[r] * linv;
            crow[16 + m] = c1[r] * linv;
        }
    }
}

// ---------------------------------------------------------------------------
// Kernel 4: ymlp — body repeated x16 for measurement.
// ---------------------------------------------------------------------------
__global__ __launch_bounds__(256) void k_ymlp(const float* __restrict__ ctx,
                                              const float* __restrict__ h,
                                              const float* __restrict__ W1,
                                              const float* __restrict__ b1,
                                              const float* __restrict__ W2,
                                              const float* __restrict__ b2,
                                              float* __restrict__ out) {
    const int b = blockIdx.x;
    const int tid = threadIdx.x;
    __shared__ __align__(16) float cs[128 * DD];
    __shared__ __align__(16) float hs[128 * DD];
    __shared__ float ys[DD][DD];
    __shared__ float yr[DD][33];
    const float* cb = ctx + (size_t)b * TT * DD;
    const float* hb = h + (size_t)b * TT * DD;
    const int e = tid & 31;
    const int d4 = (tid >> 5) * 4;
#pragma unroll 1
    for (int rep = 0; rep < REP; ++rep) {
        __syncthreads();
        float acc[4] = {0.f, 0.f, 0.f, 0.f};
        for (int kt = 0; kt < 8; ++kt) {
            const float4* s1 = (const float4*)(cb + (size_t)kt * 128 * DD);
            const float4* s2 = (const float4*)(hb + (size_t)kt * 128 * DD);
            float4* t1 = (float4*)cs;
            float4* t2 = (float4*)hs;
#pragma unroll
            for (int n = 0; n < 4; ++n) {
                t1[tid + n * 256] = s1[tid + n * 256];
                t2[tid + n * 256] = s2[tid + n * 256];
            }
            __syncthreads();
#pragma unroll 2
            for (int s = 0; s < 128; ++s) {
                float hv = hs[s * DD + e];
                float4 cv = *(const float4*)&cs[s * DD + d4];
                acc[0] = fmaf(cv.x, hv, acc[0]);
                acc[1] = fmaf(cv.y, hv, acc[1]);
                acc[2] = fmaf(cv.z, hv, acc[2]);
                acc[3] = fmaf(cv.w, hv, acc[3]);
            }
            __syncthreads();
        }
#pragma unroll
        for (int r = 0; r < 4; ++r) ys[d4 + r][e] = acc[r];
        __syncthreads();
#pragma unroll
        for (int r = 0; r < 4; ++r) {
            float v = b1[e];
#pragma unroll
            for (int ee = 0; ee < DD; ++ee) v += ys[d4 + r][ee] * W1[ee * DD + e];
            yr[d4 + r][e] = fmaxf(v, 0.0f);
        }
        __syncthreads();
        if (tid < DD) {
            float v = b2[0];
#pragma unroll
            for (int ee = 0; ee < DD; ++ee) v += yr[tid][ee] * W2[ee];
            out[b * DD + tid] = 1.0f / (1.0f + expf(-v));
        }
    }
}

// ---------------------------------------------------------------------------
extern "C" void kernel_launch(void* const* d_in, const int* in_sizes, int n_in,
                              void* d_out, int out_size, void* d_ws, size_t ws_size,
                              hipStream_t stream) {
    const int* ids   = (const int*)d_in[0];
    const float* emb = (const float*)d_in[1];
    const float* kl  = (const float*)d_in[2];
    const float* rk  = (const float*)d_in[3];
    const float* bl  = (const float*)d_in[4];
    const float* W1  = (const float*)d_in[5];
    const float* b1  = (const float*)d_in[6];
    const float* W2  = (const float*)d_in[7];
    const float* b2  = (const float*)d_in[8];
    float* out = (float*)d_out;

    char* ws = (char*)d_ws;
    const size_t XG_ELEMS = (size_t)BB * TT * GG;
    const size_t H_ELEMS  = (size_t)BB * TT * DD;
    float* xg   = (float*)ws;
    float* h    = (float*)(ws + XG_ELEMS * 4);
    float* ctx  = (float*)(ws + (XG_ELEMS + H_ELEMS) * 4);
    int* list   = (int*)  (ws + (XG_ELEMS + 2 * H_ELEMS) * 4);
    u16* hh = (u16*)ws;
    u16* hl = (u16*)(ws + H_ELEMS * 2);
    u16* th = (u16*)(ws + H_ELEMS * 4);
    u16* tl = (u16*)(ws + H_ELEMS * 6);

    k_xg<<<512, 128, 0, stream>>>(ids, emb, kl, bl, xg);
    k_lstm_scan<<<BB + 1, 64, 0, stream>>>(xg, rk, h, ids, list, out + BB * DD);
    k_cvt<<<256, 256, 0, stream>>>(h, hh, hl, th, tl);
    k_attn<<<BB * 16, 256, 0, stream>>>(hh, hl, th, tl, ctx);
    k_ymlp<<<BB, 256, 0, stream>>>(ctx, h, W1, b1, W2, b2, out);
}

// Round 13
// 541.138 us; speedup vs baseline: 5.7190x; 5.7190x over previous
//
#include <hip/hip_runtime.h>
#include <math.h>

#define BB 64
#define TT 1024
#define DD 32
#define GG 128   // 4*D
#define VOCABN 10000
#define QLEN 100

typedef short short8 __attribute__((ext_vector_type(8)));   // 8 bf16 in 4 VGPRs
typedef float floatx4 __attribute__((ext_vector_type(4)));
typedef unsigned short u16;

__device__ __forceinline__ float fsig(float x) {
    return __builtin_amdgcn_rcpf(1.0f + __expf(-x));
}
__device__ __forceinline__ float readlane_f(float v, int l) {
    return __int_as_float(__builtin_amdgcn_readlane(__float_as_int(v), l));
}
__device__ __forceinline__ u16 f2bf_rne(float x) {
    unsigned u = __float_as_uint(x);
    u += 0x7FFF + ((u >> 16) & 1);
    return (u16)(u >> 16);
}
__device__ __forceinline__ float bf2f(u16 s) {
    return __uint_as_float(((unsigned)s) << 16);
}

// ---------------------------------------------------------------------------
// Kernel 1: xg — barrier-free: wave-private emb staging, 2 gate cols/lane.
// Wave w of each block handles alternating 4-token groups; same-wave LDS
// ordering needs no __syncthreads.
// ---------------------------------------------------------------------------
__global__ __launch_bounds__(128, 2) void k_xg(const int* __restrict__ ids,
                                               const float* __restrict__ emb,
                                               const float* __restrict__ klstm,
                                               const float* __restrict__ bias,
                                               float* __restrict__ xg) {
    const int tid = threadIdx.x;
    const int w = tid >> 6;      // wave 0/1
    const int l = tid & 63;
    const int ja = l, jb = l + 64;
    float ka[DD], kb[DD];
#pragma unroll
    for (int d = 0; d < DD; ++d) {
        ka[d] = klstm[d * GG + ja];
        kb[d] = klstm[d * GG + jb];
    }
    const float bja = bias[ja], bjb = bias[jb];
    __shared__ float es[2][4][DD];
    const int PPB = (BB * TT) / gridDim.x;   // 128 tokens per block
    const int p0 = blockIdx.x * PPB;
    const int i0 = l >> 5, dd0 = l & 31;
    for (int p = p0 + w * 4; p < p0 + PPB; p += 8) {
#pragma unroll
        for (int k = 0; k < 2; ++k) {
            int tok = p + i0 + 2 * k;
            int id = ids[tok];
            if ((unsigned)id >= VOCABN) id = 0;
            es[w][i0 + 2 * k][dd0] = emb[id * DD + dd0];
        }
#pragma unroll
        for (int i = 0; i < 4; ++i) {
            float za = bja, zb = bjb;
#pragma unroll
            for (int d = 0; d < DD; ++d) {
                float e = es[w][i][d];
                za = fmaf(e, ka[d], za);
                zb = fmaf(e, kb[d], zb);
            }
            float* xr = &xg[(size_t)(p + i) * GG];
            xr[ja] = za;
            xr[jb] = zb;
        }
    }
}

// ---------------------------------------------------------------------------
// Kernel 2: LSTM scan — R3-EXACT (311 µs proven floor) + fused queue (blk 64).
// ---------------------------------------------------------------------------
#define UU 8
__global__
__attribute__((amdgpu_flat_work_group_size(64, 64)))
__attribute__((amdgpu_waves_per_eu(1, 1)))
void k_lstm_scan(const float* __restrict__ xg,
                 const float* __restrict__ rk,
                 float* __restrict__ hout,
                 const int* __restrict__ ids,
                 int* __restrict__ list,
                 float* __restrict__ outq) {
    const int b = blockIdx.x;
    const int l = threadIdx.x;       // 0..63
    if (b >= BB) {
        const int4* v4 = (const int4*)ids;
        const int C4 = (BB * TT) / 4 / 64;
        const int b4 = l * C4;
        int cnt = 0;
#pragma unroll 4
        for (int i = 0; i < C4; ++i) {
            int4 v = v4[b4 + i];
            cnt += (v.x == 0 || (unsigned)v.x >= VOCABN);
            cnt += (v.y == 0 || (unsigned)v.y >= VOCABN);
            cnt += (v.z == 0 || (unsigned)v.z >= VOCABN);
            cnt += (v.w == 0 || (unsigned)v.w >= VOCABN);
        }
        int scan = cnt;
#pragma unroll
        for (int o = 1; o < 64; o <<= 1) {
            int nn = __shfl_up(scan, o);
            if (l >= o) scan += nn;
        }
        const int total = __shfl(scan, 63);
        int off = scan - cnt;
        const int base = l * (C4 * 4);
#pragma unroll 4
        for (int i = 0; i < C4; ++i) {
            int4 v = v4[b4 + i];
            if (v.x == 0 || (unsigned)v.x >= VOCABN) list[off++] = base + 4 * i;
            if (v.y == 0 || (unsigned)v.y >= VOCABN) list[off++] = base + 4 * i + 1;
            if (v.z == 0 || (unsigned)v.z >= VOCABN) list[off++] = base + 4 * i + 2;
            if (v.w == 0 || (unsigned)v.w >= VOCABN) list[off++] = base + 4 * i + 3;
        }
        __threadfence();
        const int Kc = total < QLEN ? total : QLEN;
        for (int t = l; t < QLEN; t += 64) {
            float ii = -1.0f, jj = -1.0f;
            if (t >= QLEN - Kc) {
                int pos = list[total - QLEN + t];
                ii = (float)(pos >> 10);
                jj = (float)(pos & (TT - 1));
            }
            outq[2 * t] = ii;
            outq[2 * t + 1] = jj;
        }
        return;
    }
    const int d = l & 31;
    const bool hi = l >= 32;
    const int ga = (hi ? 32 : 0) + d;
    const int gb = (hi ? 96 : 64) + d;
    float rka[DD], rkb[DD];
#pragma unroll
    for (int k = 0; k < DD; ++k) { rka[k] = rk[k * GG + ga]; rkb[k] = rk[k * GG + gb]; }
    const float* xgb = xg + (size_t)b * TT * GG;
    float* hb = hout + (size_t)b * TT * DD;

    float pa[UU], pb[UU];
#pragma unroll
    for (int u = 0; u < UU; ++u) { pa[u] = xgb[u * GG + ga]; pb[u] = xgb[u * GG + gb]; }

    float h = 0.0f, c = 0.0f;
    for (int t0 = 0; t0 < TT; t0 += UU) {
        float na[UU], nb[UU];
        const int tn0 = (t0 + UU < TT) ? (t0 + UU) : t0;
#pragma unroll
        for (int u = 0; u < UU; ++u) {
            na[u] = xgb[(tn0 + u) * GG + ga];
            nb[u] = xgb[(tn0 + u) * GG + gb];
        }
#pragma unroll
        for (int u = 0; u < UU; ++u) {
            float za0 = pa[u], zb0 = pb[u];
            float za1 = 0.f, za2 = 0.f, za3 = 0.f;
            float zb1 = 0.f, zb2 = 0.f, zb3 = 0.f;
#pragma unroll
            for (int k = 0; k < DD; k += 4) {
                float h0 = readlane_f(h, k);
                float h1 = readlane_f(h, k + 1);
                float h2 = readlane_f(h, k + 2);
                float h3 = readlane_f(h, k + 3);
                za0 = fmaf(h0, rka[k], za0);     zb0 = fmaf(h0, rkb[k], zb0);
                za1 = fmaf(h1, rka[k + 1], za1); zb1 = fmaf(h1, rkb[k + 1], zb1);
                za2 = fmaf(h2, rka[k + 2], za2); zb2 = fmaf(h2, rkb[k + 2], zb2);
                za3 = fmaf(h3, rka[k + 3], za3); zb3 = fmaf(h3, rkb[k + 3], zb3);
            }
            float za = (za0 + za1) + (za2 + za3);
            float zb = (zb0 + zb1) + (zb2 + zb3);
            float a = fsig(za);
            float zbm = hi ? zb : 2.0f * zb;
            float s2 = fsig(zbm);
            float bv = hi ? s2 : 2.0f * s2 - 1.0f;
            float fg = __shfl_xor(a, 32);
            float og = __shfl_xor(bv, 32);
            c = fmaf(fg, c, a * bv);
            float tc = 2.0f * fsig(2.0f * c) - 1.0f;
            h = og * tc;
            if (!hi) hb[(t0 + u) * DD + d] = h;
        }
#pragma unroll
        for (int u = 0; u < UU; ++u) { pa[u] = na[u]; pb[u] = nb[u]; }
    }
}

// ---------------------------------------------------------------------------
// Kernel 2.5: cvt — XCD-swizzled decode (b = blk&63) so each batch's bf16
// data is produced on the same XCD (b%8) that k_attn consumes it on.
// ---------------------------------------------------------------------------
__global__ __launch_bounds__(256) void k_cvt(const float* __restrict__ h,
                                             u16* __restrict__ hh, u16* __restrict__ hl,
                                             u16* __restrict__ th, u16* __restrict__ tl) {
    const int b = blockIdx.x & 63;
    const int seg = blockIdx.x >> 6;
    const int tid = threadIdx.x;
    const float* hsrc = h + (size_t)b * TT * DD;
    const size_t rb = (size_t)b * TT * DD;
    const size_t tb = (size_t)b * DD * TT;
    __shared__ float tile[64][33];
    for (int t0 = seg * 256; t0 < seg * 256 + 256; t0 += 64) {
#pragma unroll
        for (int n = 0; n < 2; ++n) {
            int idx = tid + n * 256;
            int row = idx >> 3, c4 = idx & 7;
            float4 v = *(const float4*)&hsrc[(size_t)(t0 + row) * DD + c4 * 4];
            float xs[4] = {v.x, v.y, v.z, v.w};
            u16 hi4[4], lo4[4];
#pragma unroll
            for (int i = 0; i < 4; ++i) {
                tile[row][c4 * 4 + i] = xs[i];
                hi4[i] = f2bf_rne(xs[i]);
                lo4[i] = f2bf_rne(xs[i] - bf2f(hi4[i]));
            }
            ushort4 hv = {hi4[0], hi4[1], hi4[2], hi4[3]};
            ushort4 lv = {lo4[0], lo4[1], lo4[2], lo4[3]};
            *(ushort4*)&hh[rb + (size_t)(t0 + row) * DD + c4 * 4] = hv;
            *(ushort4*)&hl[rb + (size_t)(t0 + row) * DD + c4 * 4] = lv;
        }
        __syncthreads();
#pragma unroll
        for (int n = 0; n < 8; ++n) {
            int flat = tid + n * 256;
            int d = flat >> 6, tt = flat & 63;
            float x = tile[tt][d];
            u16 hv = f2bf_rne(x);
            u16 lv = f2bf_rne(x - bf2f(hv));
            th[tb + (size_t)d * TT + t0 + tt] = hv;
            tl[tb + (size_t)d * TT + t0 + tt] = lv;
        }
        __syncthreads();
    }
}

// ---------------------------------------------------------------------------
// Kernel 3: attention on MFMA (R9 math, absmax 0.0 verified) with:
// (a) XCD swizzle: b = blk&63 -> all 16 blocks of a batch on XCD b%8, the
//     batch's 2 MB of bf16 K/V stays resident in that XCD's 4 MB L2
//     (R12 measurement: attn was FETCH-bound, 68 MB refetch @774 GB/s);
// (b) register double-buffered prefetch of the 8 K/V fragments.
// ---------------------------------------------------------------------------
__global__ __launch_bounds__(256, 4) void k_attn(const u16* __restrict__ hh,
                                                 const u16* __restrict__ hl,
                                                 const u16* __restrict__ th,
                                                 const u16* __restrict__ tl,
                                                 float* __restrict__ ctx) {
    __shared__ u16 plds[4 * 16 * 40];
    const int tid = threadIdx.x;
    const int w = tid >> 6;
    const int l = tid & 63;
    const int m = l & 15;
    const int g = l >> 4;
    const int b = blockIdx.x & 63;              // XCD swizzle: XCD = b % 8
    const int qt = (blockIdx.x >> 6) * 4 + w;   // 0..63
    const int q0 = qt * 16;
    const size_t rb = (size_t)b * TT * DD;
    const size_t tb = (size_t)b * DD * TT;

    const short8 Qh = *(const short8*)&hh[rb + (size_t)(q0 + m) * DD + g * 8];
    const short8 Ql = *(const short8*)&hl[rb + (size_t)(q0 + m) * DD + g * 8];
    short8 ONES;
#pragma unroll
    for (int j = 0; j < 8; ++j) ONES[j] = (short)0x3F80;
    u16* mylds = plds + w * (16 * 40);

    floatx4 c0 = {0.f, 0.f, 0.f, 0.f};
    floatx4 c1 = {0.f, 0.f, 0.f, 0.f};
    floatx4 la = {0.f, 0.f, 0.f, 0.f};

    // preload kp = 0
    short8 KhA = *(const short8*)&hh[rb + (size_t)(m) * DD + g * 8];
    short8 KlA = *(const short8*)&hl[rb + (size_t)(m) * DD + g * 8];
    short8 KhB = *(const short8*)&hh[rb + (size_t)(16 + m) * DD + g * 8];
    short8 KlB = *(const short8*)&hl[rb + (size_t)(16 + m) * DD + g * 8];
    short8 Vh0 = *(const short8*)&th[tb + (size_t)m * TT + g * 8];
    short8 Vl0 = *(const short8*)&tl[tb + (size_t)m * TT + g * 8];
    short8 Vh1 = *(const short8*)&th[tb + (size_t)(16 + m) * TT + g * 8];
    short8 Vl1 = *(const short8*)&tl[tb + (size_t)(16 + m) * TT + g * 8];

#pragma unroll 1
    for (int kp = 0; kp < 32; ++kp) {
        const int kn = (kp < 31) ? (kp + 1) * 32 : 0;   // last iter: dummy
        // issue next-iteration loads first (vmcnt-covered by compute below)
        short8 nKhA = *(const short8*)&hh[rb + (size_t)(kn + m) * DD + g * 8];
        short8 nKlA = *(const short8*)&hl[rb + (size_t)(kn + m) * DD + g * 8];
        short8 nKhB = *(const short8*)&hh[rb + (size_t)(kn + 16 + m) * DD + g * 8];
        short8 nKlB = *(const short8*)&hl[rb + (size_t)(kn + 16 + m) * DD + g * 8];
        short8 nVh0 = *(const short8*)&th[tb + (size_t)m * TT + kn + g * 8];
        short8 nVl0 = *(const short8*)&tl[tb + (size_t)m * TT + kn + g * 8];
        short8 nVh1 = *(const short8*)&th[tb + (size_t)(16 + m) * TT + kn + g * 8];
        short8 nVl1 = *(const short8*)&tl[tb + (size_t)(16 + m) * TT + kn + g * 8];

        floatx4 sA = {0.f, 0.f, 0.f, 0.f};
        floatx4 sB = {0.f, 0.f, 0.f, 0.f};
        sA = __builtin_amdgcn_mfma_f32_16x16x32_bf16(Qh, KhA, sA, 0, 0, 0);
        sA = __builtin_amdgcn_mfma_f32_16x16x32_bf16(Qh, KlA, sA, 0, 0, 0);
        sA = __builtin_amdgcn_mfma_f32_16x16x32_bf16(Ql, KhA, sA, 0, 0, 0);
        sB = __builtin_amdgcn_mfma_f32_16x16x32_bf16(Qh, KhB, sB, 0, 0, 0);
        sB = __builtin_amdgcn_mfma_f32_16x16x32_bf16(Qh, KlB, sB, 0, 0, 0);
        sB = __builtin_amdgcn_mfma_f32_16x16x32_bf16(Ql, KhB, sB, 0, 0, 0);
#pragma unroll
        for (int r = 0; r < 4; ++r) {
            mylds[(g * 4 + r) * 40 + m]      = f2bf_rne(__expf(sA[r]));
            mylds[(g * 4 + r) * 40 + 16 + m] = f2bf_rne(__expf(sB[r]));
        }
        const short8 P = *(const short8*)&mylds[m * 40 + g * 8];
        c0 = __builtin_amdgcn_mfma_f32_16x16x32_bf16(P, Vh0, c0, 0, 0, 0);
        c0 = __builtin_amdgcn_mfma_f32_16x16x32_bf16(P, Vl0, c0, 0, 0, 0);
        c1 = __builtin_amdgcn_mfma_f32_16x16x32_bf16(P, Vh1, c1, 0, 0, 0);
        c1 = __builtin_amdgcn_mfma_f32_16x16x32_bf16(P, Vl1, c1, 0, 0, 0);
        la = __builtin_amdgcn_mfma_f32_16x16x32_bf16(P, ONES, la, 0, 0, 0);

        KhA = nKhA; KlA = nKlA; KhB = nKhB; KlB = nKlB;
        Vh0 = nVh0; Vl0 = nVl0; Vh1 = nVh1; Vl1 = nVl1;
    }
#pragma unroll
    for (int r = 0; r < 4; ++r) {
        float linv = __builtin_amdgcn_rcpf(la[r]);
        float* crow = ctx + rb + (size_t)(q0 + g * 4 + r) * DD;
        crow[m]      = c0[r] * linv;
        crow[16 + m] = c1[r] * linv;
    }
}

// ---------------------------------------------------------------------------
// Kernel 4: ymlp — R10 version (d4 remap, ds_read_b128). blk = b so its
// ctx/h reads hit the same XCD L2 attn wrote (b%8).
// ---------------------------------------------------------------------------
__global__ __launch_bounds__(256) void k_ymlp(const float* __restrict__ ctx,
                                              const float* __restrict__ h,
                                              const float* __restrict__ W1,
                                              const float* __restrict__ b1,
                                              const float* __restrict__ W2,
                                              const float* __restrict__ b2,
                                              float* __restrict__ out) {
    const int b = blockIdx.x;
    const int tid = threadIdx.x;
    __shared__ __align__(16) float cs[128 * DD];
    __shared__ __align__(16) float hs[128 * DD];
    const float* cb = ctx + (size_t)b * TT * DD;
    const float* hb = h + (size_t)b * TT * DD;
    const int e = tid & 31;
    const int d4 = (tid >> 5) * 4;
    float acc[4] = {0.f, 0.f, 0.f, 0.f};
    for (int kt = 0; kt < 8; ++kt) {
        const float4* s1 = (const float4*)(cb + (size_t)kt * 128 * DD);
        const float4* s2 = (const float4*)(hb + (size_t)kt * 128 * DD);
        float4* t1 = (float4*)cs;
        float4* t2 = (float4*)hs;
#pragma unroll
        for (int n = 0; n < 4; ++n) {
            t1[tid + n * 256] = s1[tid + n * 256];
            t2[tid + n * 256] = s2[tid + n * 256];
        }
        __syncthreads();
#pragma unroll 2
        for (int s = 0; s < 128; ++s) {
            float hv = hs[s * DD + e];
            float4 cv = *(const float4*)&cs[s * DD + d4];
            acc[0] = fmaf(cv.x, hv, acc[0]);
            acc[1] = fmaf(cv.y, hv, acc[1]);
            acc[2] = fmaf(cv.z, hv, acc[2]);
            acc[3] = fmaf(cv.w, hv, acc[3]);
        }
        __syncthreads();
    }
    __shared__ float ys[DD][DD];
#pragma unroll
    for (int r = 0; r < 4; ++r) ys[d4 + r][e] = acc[r];
    __syncthreads();
    __shared__ float yr[DD][33];
#pragma unroll
    for (int r = 0; r < 4; ++r) {
        float v = b1[e];
#pragma unroll
        for (int ee = 0; ee < DD; ++ee) v += ys[d4 + r][ee] * W1[ee * DD + e];
        yr[d4 + r][e] = fmaxf(v, 0.0f);
    }
    __syncthreads();
    if (tid < DD) {
        float v = b2[0];
#pragma unroll
        for (int ee = 0; ee < DD; ++ee) v += yr[tid][ee] * W2[ee];
        out[b * DD + tid] = 1.0f / (1.0f + expf(-v));
    }
}

// ---------------------------------------------------------------------------
extern "C" void kernel_launch(void* const* d_in, const int* in_sizes, int n_in,
                              void* d_out, int out_size, void* d_ws, size_t ws_size,
                              hipStream_t stream) {
    const int* ids   = (const int*)d_in[0];
    const float* emb = (const float*)d_in[1];
    const float* kl  = (const float*)d_in[2];
    const float* rk  = (const float*)d_in[3];
    const float* bl  = (const float*)d_in[4];
    const float* W1  = (const float*)d_in[5];
    const float* b1  = (const float*)d_in[6];
    const float* W2  = (const float*)d_in[7];
    const float* b2  = (const float*)d_in[8];
    float* out = (float*)d_out;

    char* ws = (char*)d_ws;
    const size_t XG_ELEMS = (size_t)BB * TT * GG;   // 8,388,608 (32 MB)
    const size_t H_ELEMS  = (size_t)BB * TT * DD;   // 2,097,152 (8 MB)
    float* xg   = (float*)ws;
    float* h    = (float*)(ws + XG_ELEMS * 4);
    float* ctx  = (float*)(ws + (XG_ELEMS + H_ELEMS) * 4);
    int* list   = (int*)  (ws + (XG_ELEMS + 2 * H_ELEMS) * 4);
    // bf16 arrays overlay the xg region (xg dead after k_lstm_scan):
    u16* hh = (u16*)ws;
    u16* hl = (u16*)(ws + H_ELEMS * 2);
    u16* th = (u16*)(ws + H_ELEMS * 4);
    u16* tl = (u16*)(ws + H_ELEMS * 6);

    k_xg<<<512, 128, 0, stream>>>(ids, emb, kl, bl, xg);
    k_lstm_scan<<<BB + 1, 64, 0, stream>>>(xg, rk, h, ids, list, out + BB * DD);
    k_cvt<<<256, 256, 0, stream>>>(h, hh, hl, th, tl);
    k_attn<<<BB * 16, 256, 0, stream>>>(hh, hl, th, tl, ctx);
    k_ymlp<<<BB, 256, 0, stream>>>(ctx, h, W1, b1, W2, b2, out);
}